// Round 10
// baseline (157.692 us; speedup 1.0000x reference)
//
#include <hip/hip_runtime.h>

#define BATCH 4096
#define DICT  16384
#define KDIM  512
#define CAT   128
#define ND    16              // split-K over dict
#define DSLICE (DICT/ND)      // 1024
#define DCH   128             // d-chunk per dc iteration
#define BT    256             // b rows per block (4 waves x 64)

typedef __attribute__((ext_vector_type(4))) float          f32x4;
typedef __attribute__((ext_vector_type(8))) short          short8;
typedef __attribute__((ext_vector_type(8))) unsigned short ushort8;
typedef __attribute__((ext_vector_type(4))) int            intx4;

__device__ __forceinline__ unsigned short f2bf(float f) {
  unsigned int u = __float_as_uint(f);
  return (unsigned short)((u + 0x7fffu + ((u >> 16) & 1u)) >> 16);  // RNE
}

__device__ __forceinline__ unsigned int cvtpk_bf16(float lo, float hi) {
  unsigned int r;
  asm volatile("v_cvt_pk_bf16_f32 %0, %1, %2" : "=v"(r) : "v"(lo), "v"(hi));
  return r;
}

#define AS1 __attribute__((address_space(1)))
#define AS3 __attribute__((address_space(3)))
__device__ __forceinline__ void gl_lds16(const void* g, void* l) {
  // 16B/lane; LDS dest = wave-uniform base + lane*16 (linear). Swizzle is
  // pre-applied on the GLOBAL source address (m173 pattern).
  __builtin_amdgcn_global_load_lds((AS1 void*)(g), (AS3 void*)(l), 16, 0, 0);
}

template <int N>
__device__ __forceinline__ void waitv() {
  if constexpr (N == 0)       asm volatile("s_waitcnt vmcnt(0)" ::: "memory");
  else if constexpr (N == 12) asm volatile("s_waitcnt vmcnt(12)" ::: "memory");
  else                        asm volatile("s_waitcnt vmcnt(14)" ::: "memory");
  __builtin_amdgcn_sched_barrier(0);   // rule #18: pin ops after the waitcnt
}

#define MFMA16(a, b, c) __builtin_amdgcn_mfma_f32_16x16x32_bf16((a), (b), (c), 0, 0, 0)

// ---------- prep: rows -> bf16 + sum of squares (x and keys) ----------
__global__ void prep_rows(const float* __restrict__ in,
                          unsigned short* __restrict__ ob,
                          float* __restrict__ sums) {
  const int lane = threadIdx.x & 63, wv = threadIdx.x >> 6;
  const int row = blockIdx.x * 4 + wv;
  const float* rp = in + ((size_t)row << 9);
  float4 a = *(const float4*)(rp + lane * 8);
  float4 b = *(const float4*)(rp + lane * 8 + 4);
  float s = a.x*a.x + a.y*a.y + a.z*a.z + a.w*a.w
          + b.x*b.x + b.y*b.y + b.z*b.z + b.w*b.w;
  ushort8 o;
  o[0]=f2bf(a.x); o[1]=f2bf(a.y); o[2]=f2bf(a.z); o[3]=f2bf(a.w);
  o[4]=f2bf(b.x); o[5]=f2bf(b.y); o[6]=f2bf(b.z); o[7]=f2bf(b.w);
  *(ushort8*)(ob + ((size_t)row << 9) + lane * 8) = o;
  #pragma unroll
  for (int m = 32; m; m >>= 1) s += __shfl_xor(s, m);
  if (lane == 0) sums[row] = s;
}

// ---------- prep: V (16384x128) -> Vt bf16 (128x16384), sigma-permuted ----------
// Within each 32-d block, stored position p = 8q+j holds source d =
//   4q + j (j<4) ;  16 + 4q + j-4 (j>=4)   [R9-verified]
__global__ void prep_vt(const float* __restrict__ V,
                        unsigned short* __restrict__ Vt) {
  __shared__ float t[64][129];
  const int d0 = blockIdx.x * 64;
  const int tid = threadIdx.x;
  #pragma unroll
  for (int j = 0; j < 32; ++j) {
    int idx = j * 256 + tid;
    t[idx >> 7][idx & 127] = V[((size_t)d0 << 7) + idx];
  }
  __syncthreads();
  #pragma unroll
  for (int j = 0; j < 32; ++j) {
    int idx = j * 256 + tid;
    int cc = idx >> 6, dd = idx & 63;
    int p = dd & 31, qq = p >> 3, jj = p & 7;
    int src = (dd & 32) + 4 * qq + ((jj < 4) ? jj : (12 + jj));
    Vt[((size_t)cc << 14) + d0 + dd] = f2bf(t[src][cc]);
  }
}

// ---------- fused kernel: 256 threads (4 waves, 1 wave/SIMD -> 512-VGPR budget) ----------
// Wave tile 128d x 64b: S[8][4], acc[4][8].  DCH=128.  LDS 128KB exactly:
//   As dbuf 2x16KB | Bs dbuf 2x32KB | VsA 16KB | VsB 16KB
// Per k-step: s_barrier ; stage(next,12 calls) ; s_waitcnt vmcnt(12|14) ; s_barrier ; MFMA.
// In-register P via sigma-Vt + cvt_pk (R9-verified).  All frag/staging math R9-verbatim.
__global__ __launch_bounds__(256, 1)
void varkeys_fused(const unsigned short* __restrict__ xb,
                   const unsigned short* __restrict__ kb,
                   const unsigned short* __restrict__ vt,
                   const float* __restrict__ sx,
                   const float* __restrict__ sk,
                   float* __restrict__ kvp) {
  __shared__ __attribute__((aligned(16))) char lds[131072];
  char* const VsA = lds + 98304;             // d 0..63 of chunk
  char* const VsB = lds + 114688;            // d 64..127

  const int tid  = threadIdx.x;
  const int lane = tid & 63;
  const int wv   = tid >> 6;                 // 0..3 = bw
  const int c    = lane & 15;
  const int h    = lane >> 4;                // = q
  const int sw   = (lane & 7) << 4;
  const int l3   = lane >> 3;

  const int bid    = blockIdx.x;
  const int btile  = bid & 15;
  const int dslice = bid >> 4;
  const int b0     = btile * BT;
  const int dbase  = dslice * DSLICE;

  float sxv[4];
  #pragma unroll
  for (int fj = 0; fj < 4; ++fj) sxv[fj] = sx[b0 + wv * 64 + fj * 16 + c];

  // staging per-thread constants (R9-verified linear-dest <-> swizzled-source)
  const int rowS = wv * 8 + l3;                        // row within 32-row call
  const int ofs  = (((lane & 7) ^ l3) << 4);           // swizzled in-row offset

  const char* xbB = (const char*)xb;
  const char* kbB = (const char*)kb;
  const char* vtB = (const char*)vt;

  const f32x4 zero = {0.f, 0.f, 0.f, 0.f};
  f32x4 acc[4][8];
  #pragma unroll
  for (int j = 0; j < 4; ++j)
    #pragma unroll
    for (int n = 0; n < 8; ++n) acc[j][n] = zero;

  // ---- stage one 64-k step of keys(128 rows, 4 calls) + x(256 rows, 8 calls) ----
  auto stageAB = [&](int ns) {
    const int dg2 = dbase + (ns >> 3) * DCH;
    const int kb2 = (ns & 7) << 7;
    char* A2 = lds + (ns & 1) * 16384;
    char* B2 = lds + 32768 + (ns & 1) * 32768;
    #pragma unroll
    for (int cl = 0; cl < 4; ++cl)
      gl_lds16(kbB + ((size_t)(dg2 + cl * 32 + rowS) << 10) + kb2 + ofs,
               A2 + cl * 4096 + wv * 1024);
    #pragma unroll
    for (int cl = 0; cl < 8; ++cl)
      gl_lds16(xbB + ((size_t)(b0 + cl * 32 + rowS) << 10) + kb2 + ofs,
               B2 + cl * 4096 + wv * 1024);
  };

  stageAB(0);   // prologue: (dc=0, kk=0) -> buf0

  f32x4 skq[8];

  for (int dc = 0; dc < DSLICE / DCH; ++dc) {
    const int dg = dbase + dc * DCH;

    f32x4 S[8][4];
    #pragma unroll
    for (int i = 0; i < 8; ++i)
      #pragma unroll
      for (int fj = 0; fj < 4; ++fj) S[i][fj] = zero;

    #pragma unroll
    for (int kk = 0; kk < 8; ++kk) {
      __builtin_amdgcn_s_barrier();          // A: all waves done reading buf[kk&1^1]
      if (kk == 0) {                         // sk for THIS dc (drained by waitv)
        #pragma unroll
        for (int i = 0; i < 8; ++i)
          skq[i] = *(const f32x4*)(sk + dg + i * 16 + h * 4);
      }
      const int ns = dc * 8 + kk + 1;
      if (ns < 64) stageAB(ns);
      if (kk >= 2 && kk <= 5) {              // V: 2 calls/kk, half A at kk=2,3; B at 4,5
        char* const VsH = (kk < 4) ? VsA : VsB;
        const int hv = (kk < 4) ? 0 : 1;
        #pragma unroll
        for (int t = 0; t < 2; ++t) {
          const int cl = ((kk - 2) & 1) * 2 + t;   // 0..3 per half
          gl_lds16(vtB + ((size_t)(cl * 32 + rowS) << 15)
                       + ((size_t)(dg + hv * 64) << 1) + ofs,
                   VsH + cl * 4096 + wv * 1024);
        }
      }
      if (ns == 64) waitv<0>();
      else if (kk >= 2 && kk <= 5) waitv<14>();
      else waitv<12>();
      __builtin_amdgcn_s_barrier();          // B: everyone's stage(this buf) landed
      __builtin_amdgcn_sched_barrier(0);

      // GEMM1 k-step on buf[kk&1]: 24 ds_reads, 64 MFMA (R9 frag math, wider tile)
      const char* As = lds + (kk & 1) * 16384;
      const char* Bs = lds + 32768 + (kk & 1) * 32768;
      #pragma unroll
      for (int kf = 0; kf < 2; ++kf) {
        const int ko = (kf * 64 + h * 16) ^ sw;
        short8 bf[4];
        #pragma unroll
        for (int fj = 0; fj < 4; ++fj)
          bf[fj] = *(const short8*)(Bs + ((wv * 64 + fj * 16 + c) << 7) + ko);
        #pragma unroll
        for (int i = 0; i < 8; ++i) {
          short8 af = *(const short8*)(As + ((i * 16 + c) << 7) + ko);
          #pragma unroll
          for (int fj = 0; fj < 4; ++fj)
            S[i][fj] = MFMA16(af, bf[fj], S[i][fj]);
        }
      }
    }

    // transform + in-register P (sigma layout, R9-verified) + GEMM2
    #pragma unroll
    for (int hv = 0; hv < 2; ++hv) {
      const char* VsH = hv ? VsB : VsA;
      #pragma unroll
      for (int dkh = 0; dkh < 2; ++dkh) {
        const int dk = hv * 2 + dkh;
        short8 pa[4];
        #pragma unroll
        for (int fj = 0; fj < 4; ++fj) {
          const float sv = sxv[fj];
          const f32x4 sA = S[2 * dk][fj];
          const f32x4 sB = S[2 * dk + 1][fj];
          const f32x4 kA = skq[2 * dk];
          const f32x4 kB = skq[2 * dk + 1];
          float a0 = 10000.f * __builtin_amdgcn_rcpf(kA[0] + sv - 2.f * sA[0] + 1.f);
          float a1 = 10000.f * __builtin_amdgcn_rcpf(kA[1] + sv - 2.f * sA[1] + 1.f);
          float a2 = 10000.f * __builtin_amdgcn_rcpf(kA[2] + sv - 2.f * sA[2] + 1.f);
          float a3 = 10000.f * __builtin_amdgcn_rcpf(kA[3] + sv - 2.f * sA[3] + 1.f);
          float b0f = 10000.f * __builtin_amdgcn_rcpf(kB[0] + sv - 2.f * sB[0] + 1.f);
          float b1f = 10000.f * __builtin_amdgcn_rcpf(kB[1] + sv - 2.f * sB[1] + 1.f);
          float b2f = 10000.f * __builtin_amdgcn_rcpf(kB[2] + sv - 2.f * sB[2] + 1.f);
          float b3f = 10000.f * __builtin_amdgcn_rcpf(kB[3] + sv - 2.f * sB[3] + 1.f);
          intx4 fw;
          fw[0] = (int)cvtpk_bf16(a0, a1);
          fw[1] = (int)cvtpk_bf16(a2, a3);
          fw[2] = (int)cvtpk_bf16(b0f, b1f);
          fw[3] = (int)cvtpk_bf16(b2f, b3f);
          pa[fj] = *(short8*)&fw;
        }
        const int ko = (dkh * 64 + h * 16) ^ sw;
        #pragma unroll
        for (int fc = 0; fc < 8; ++fc) {
          short8 vb = *(const short8*)(VsH + ((fc * 16 + c) << 7) + ko);
          #pragma unroll
          for (int fj = 0; fj < 4; ++fj)
            acc[fj][fc] = MFMA16(pa[fj], vb, acc[fj][fc]);
        }
      }
    }
  }

  // epilogue: bounce acc through per-wave LDS (32KB each), store full lines
  __syncthreads();   // all main-loop LDS reads done; reuse whole LDS
  float* eb = (float*)(lds + (wv << 15));
  #pragma unroll
  for (int fj = 0; fj < 4; ++fj)
    #pragma unroll
    for (int r = 0; r < 4; ++r) {
      const int brow = fj * 16 + h * 4 + r;
      #pragma unroll
      for (int fc = 0; fc < 8; ++fc)
        eb[(brow << 7) + fc * 16 + c] = acc[fj][fc][r];
    }
  __syncthreads();
  // coalesced copy: 256 threads, 32 iters x 4 rows of 512B
  float* op = kvp + (((size_t)dslice * BATCH + b0) << 7);
  const float* ebase = (const float*)lds;
  #pragma unroll
  for (int t = 0; t < 32; ++t) {
    const int row = t * 8 + (tid >> 5);
    f32x4 v = *(const f32x4*)(ebase + (row << 7) + ((tid & 31) << 2));
    *(f32x4*)(op + (((size_t)row) << 7) + ((tid & 31) << 2)) = v;
  }
}

// ---------- reduce ND slices + row-normalize ----------
__global__ void reduce_norm(const float* __restrict__ part, float* __restrict__ out) {
  const int lane = threadIdx.x & 63, wv = threadIdx.x >> 6;
  const int b = blockIdx.x * 4 + wv;
  float v0 = 0.f, v1 = 0.f;
  #pragma unroll
  for (int s = 0; s < ND; ++s) {
    const float* p = part + ((((size_t)s << 12) + b) << 7);
    v0 += p[lane]; v1 += p[lane + 64];
  }
  float t = v0 + v1;
  #pragma unroll
  for (int m = 32; m; m >>= 1) t += __shfl_xor(t, m);
  out[((size_t)b << 7) + lane]      = v0 / t;
  out[((size_t)b << 7) + lane + 64] = v1 / t;
}

extern "C" void kernel_launch(void* const* d_in, const int* in_sizes, int n_in,
                              void* d_out, int out_size, void* d_ws, size_t ws_size,
                              hipStream_t stream) {
  (void)in_sizes; (void)n_in; (void)out_size; (void)ws_size;
  const float* x    = (const float*)d_in[0];
  const float* keys = (const float*)d_in[1];
  const float* V    = (const float*)d_in[2];
  float* out = (float*)d_out;
  char* ws = (char*)d_ws;
  // ws (57MB): xb 4M | kb 16M @4M | vt 4M @20M | sx @24M | sk @24M+64K | kvp 32M @25M
  unsigned short* xb = (unsigned short*)(ws);
  unsigned short* kb = (unsigned short*)(ws + ((size_t)4 << 20));
  unsigned short* vt = (unsigned short*)(ws + ((size_t)20 << 20));
  float* sx  = (float*)(ws + ((size_t)24 << 20));
  float* sk  = (float*)(ws + ((size_t)24 << 20) + (1 << 16));
  float* kvp = (float*)(ws + ((size_t)25 << 20));

  prep_rows<<<BATCH / 4, 256, 0, stream>>>(x, xb, sx);
  prep_rows<<<DICT / 4, 256, 0, stream>>>(keys, kb, sk);
  prep_vt<<<DICT / 64, 256, 0, stream>>>(V, vt);
  varkeys_fused<<<(BATCH / BT) * ND, 256, 0, stream>>>(xb, kb, vt, sx, sk, kvp);
  reduce_norm<<<BATCH / 4, 256, 0, stream>>>(kvp, out);
}